// Round 23
// baseline (688.393 us; speedup 1.0000x reference)
//
#include <hip/hip_runtime.h>
#include <hip/hip_bf16.h>

#define NV 32000
#define NE 512
#define NH 512
#define NB 16
#define NT 128
#define NS 128

typedef __bf16 bf16x8 __attribute__((ext_vector_type(8)));
typedef float f32x4 __attribute__((ext_vector_type(4)));
typedef const __attribute__((address_space(1))) unsigned int gu32;
typedef __attribute__((address_space(3))) unsigned int lu32;

// ---------------- workspace layout (bytes) ----------------
static constexpr size_t HTAG_OFF  = 0;                                    // [2][16][512] u64
static constexpr size_t HDONE_OFF = HTAG_OFF + (size_t)2*NB*NH*8;         // [2048] u32
static constexpr size_t GIF_OFF   = HDONE_OFF + 8192;                     // [32] u32 (pad 4KB)
static constexpr size_t GI_OFF    = GIF_OFF + 4096;                       // [T][B][1536] f32
static constexpr size_t HALL_OFF  = GI_OFF + (size_t)NT*NB*3*NH*4;        // [T+1][B][512] f32
static constexpr size_t MIX_OFF   = HALL_OFF + (size_t)(NT+1)*NB*NH*4;    // [B*T][512] f32
static constexpr size_t ATTB_OFF  = MIX_OFF + (size_t)NB*NT*NH*4;         // [B*T][512] bf16
static constexpr size_t OWB_OFF   = ATTB_OFF + (size_t)NB*NT*NH*2;        // [V][512] bf16
static constexpr size_t WS_NEED   = OWB_OFF + (size_t)NV*NH*2;            // ~56 MB

// ---------------- K1: k_mid — rec (0..127) || gi + conv + attn (128..255) ----------------
// 256 blocks x 512 threads; 84KB LDS -> 1 block/CU (CU-exclusive).
// Consumers compute gi tiles first (chunk-major, per-(b,half) flags), then conv+attn.
__global__ __launch_bounds__(512, 1) void k_mid(const float* __restrict__ w_hh,
                                                const float* __restrict__ b_hh,
                                                const float* __restrict__ dh,
                                                float* __restrict__ h_all,
                                                unsigned long long* __restrict__ htag,
                                                unsigned int* __restrict__ hdone,
                                                unsigned int* __restrict__ giflag,
                                                float* __restrict__ gi_all,
                                                const int* __restrict__ tv,
                                                const float* __restrict__ emb,
                                                const float* __restrict__ w_ih,
                                                const float* __restrict__ b_ih,
                                                float* __restrict__ d_hf,
                                                const float* __restrict__ enc,
                                                const int* __restrict__ mask,
                                                const float* __restrict__ out_w,
                                                __bf16* __restrict__ owb,
                                                float* __restrict__ d_attn,
                                                float* __restrict__ mixb) {
  __shared__ char smem_raw[86016];   // 84 KB fences to 1 block/CU
  float* smem = (float*)smem_raw;
  const int tid = threadIdx.x;
  const int bid = blockIdx.x;

  if (bid < 128) {
    // ================= recurrence (proven htag protocol) =================
    const int b = bid & 15, sub = bid >> 4;
    const int hl = tid & 63, kc = tid >> 6;
    const int j = sub * 64 + hl;
    float* hbuf = smem;
    float* part = smem + 512;

    float wg[3][64];
#pragma unroll
    for (int g = 0; g < 3; ++g) {
      const float* wp = w_hh + (long long)(g * 512 + j) * NH + kc * 64;
#pragma unroll
      for (int q4 = 0; q4 < 16; ++q4) {
        float4 w4 = *(const float4*)(wp + q4 * 4);
        wg[g][q4 * 4 + 0] = w4.x; wg[g][q4 * 4 + 1] = w4.y;
        wg[g][q4 * 4 + 2] = w4.z; wg[g][q4 * 4 + 3] = w4.w;
      }
    }
    float bhr = 0.f, bhz = 0.f, bhn = 0.f;
    if (tid < 64) {
      bhr = b_hh[sub * 64 + tid];
      bhz = b_hh[512 + sub * 64 + tid];
      bhn = b_hh[1024 + sub * 64 + tid];
    }

    for (int t = 0; t < NT; ++t) {
      // gate on gi availability for this (b, half)
      if ((t & 63) == 0) {
        if (tid == 0) {
          unsigned int* gf = &giflag[b * 2 + (t >> 6)];
          int guard = 0;
          while (__hip_atomic_load(gf, __ATOMIC_RELAXED, __HIP_MEMORY_SCOPE_AGENT) < 24u &&
                 ++guard < (1 << 25)) {}
          (void)__hip_atomic_load(gf, __ATOMIC_ACQUIRE, __HIP_MEMORY_SCOPE_AGENT);
        }
        __syncthreads();
      }
      float gr = 0.f, gz = 0.f, gn = 0.f;
      if (tid < 64) {
        float* gi = gi_all + (long long)(t * 16 + b) * 1536;
        gr = __hip_atomic_load(gi + sub * 64 + tid, __ATOMIC_RELAXED, __HIP_MEMORY_SCOPE_AGENT);
        gz = __hip_atomic_load(gi + 512 + sub * 64 + tid, __ATOMIC_RELAXED, __HIP_MEMORY_SCOPE_AGENT);
        gn = __hip_atomic_load(gi + 1024 + sub * 64 + tid, __ATOMIC_RELAXED, __HIP_MEMORY_SCOPE_AGENT);
      }
      if (t == 0) {
        hbuf[tid] = dh[b * 512 + tid];
      } else {
        unsigned long long* slot = htag + ((long long)(t & 1) * NB + b) * 512 + tid;
        unsigned long long v = __hip_atomic_load(slot, __ATOMIC_RELAXED, __HIP_MEMORY_SCOPE_AGENT);
        int guard = 0;
        while ((unsigned)(v >> 32) != (unsigned)(t + 1) && ++guard < (1 << 22)) {
          v = __hip_atomic_load(slot, __ATOMIC_RELAXED, __HIP_MEMORY_SCOPE_AGENT);
        }
        union { unsigned u; float f; } c; c.u = (unsigned)v;
        hbuf[tid] = c.f;
      }
      __syncthreads();
      float ar = 0.f, az = 0.f, an = 0.f;
#pragma unroll
      for (int q4 = 0; q4 < 4; ++q4) {
        float4 h4[4];
#pragma unroll
        for (int u = 0; u < 4; ++u) h4[u] = *(const float4*)&hbuf[kc * 64 + q4 * 16 + u * 4];
#pragma unroll
        for (int u = 0; u < 4; ++u) {
          const float hh[4] = {h4[u].x, h4[u].y, h4[u].z, h4[u].w};
#pragma unroll
          for (int v = 0; v < 4; ++v) {
            const int q = q4 * 16 + u * 4 + v;
            ar = fmaf(hh[v], wg[0][q], ar);
            az = fmaf(hh[v], wg[1][q], az);
            an = fmaf(hh[v], wg[2][q], an);
          }
        }
      }
      part[(0 * 8 + kc) * 64 + hl] = ar;
      part[(1 * 8 + kc) * 64 + hl] = az;
      part[(2 * 8 + kc) * 64 + hl] = an;
      __syncthreads();
      if (tid < 64) {
        float sr = bhr, sz = bhz, sn = bhn;
#pragma unroll
        for (int c = 0; c < 8; ++c) {
          sr += part[(0 * 8 + c) * 64 + tid];
          sz += part[(1 * 8 + c) * 64 + tid];
          sn += part[(2 * 8 + c) * 64 + tid];
        }
        float r = 1.f / (1.f + expf(-(gr + sr)));
        float z = 1.f / (1.f + expf(-(gz + sz)));
        float n = tanhf(gn + r * sn);
        float hp = hbuf[sub * 64 + tid];
        float hv = (1.f - z) * n + z * hp;
        if (t < NT - 1) {
          union { float f; unsigned u; } c2; c2.f = hv;
          unsigned long long out = ((unsigned long long)(unsigned)(t + 2) << 32) | c2.u;
          __hip_atomic_store(htag + ((long long)((t + 1) & 1) * NB + b) * 512 + sub * 64 + tid, out,
                             __ATOMIC_RELAXED, __HIP_MEMORY_SCOPE_AGENT);
        }
        __hip_atomic_store(&h_all[(long long)((t + 1) * 16 + b) * 512 + sub * 64 + tid], hv,
                           __ATOMIC_RELAXED, __HIP_MEMORY_SCOPE_AGENT);
        if (t == NT - 1) d_hf[b * 512 + sub * 64 + tid] = hv;
      }
      __syncthreads();
      if (tid == 0)
        __hip_atomic_fetch_add(&hdone[t * 16 + b], 1u, __ATOMIC_RELAXED, __HIP_MEMORY_SCOPE_AGENT);
    }
    return;
  }

  // ================= consumers: gi phase, then conv + attention =================
  const int cid = bid - 128;
  // ---- phase 0: 6 gi tiles, chunk-major (all b chunk0 first) ----
  {
    float (*As)[64] = (float (*)[64])smem;
    float (*Bs)[64] = (float (*)[64])(smem + 1024);
    for (int p = 0; p < 6; ++p) {
      const int tt = p * 128 + cid;        // 0..767
      const int chunk = tt / 384;
      const int rem = tt % 384;
      const int b = rem / 24, nt = rem % 24;
      const int n0 = nt * 64;
      const int m0 = b * 128 + chunk * 64;
      float acc[2][4] = {};
      const int rl = tid >> 3;             // 0..63 staging row
      const int kq2 = (tid & 7) * 2;       // k-offset 0,2..14
      const int tvr = tv[m0 + rl];
      const float* arow = emb + (long long)tvr * NE;
      const int tm = tid & 31, tn = tid >> 5;   // 32 m-pairs x 16 n-quads
      for (int k0 = 0; k0 < NE; k0 += 16) {
        __syncthreads();
        float2 av = make_float2(0.f, 0.f);
        if (tvr != 0) av = *(const float2*)(arow + k0 + kq2);
        float2 bv = *(const float2*)(w_ih + (long long)(n0 + rl) * NE + k0 + kq2);
        As[kq2 + 0][rl] = av.x; As[kq2 + 1][rl] = av.y;
        Bs[kq2 + 0][rl] = bv.x; Bs[kq2 + 1][rl] = bv.y;
        __syncthreads();
#pragma unroll
        for (int kk = 0; kk < 16; ++kk) {
          float a0 = As[kk][tm * 2], a1 = As[kk][tm * 2 + 1];
          float4 b4 = *(const float4*)&Bs[kk][tn * 4];
          const float br[4] = {b4.x, b4.y, b4.z, b4.w};
#pragma unroll
          for (int jj = 0; jj < 4; ++jj) {
            acc[0][jj] = fmaf(a0, br[jj], acc[0][jj]);
            acc[1][jj] = fmaf(a1, br[jj], acc[1][jj]);
          }
        }
      }
#pragma unroll
      for (int i = 0; i < 2; ++i) {
        int r = m0 + tm * 2 + i;
        long long gb = (long long)((r & 127) * 16 + (r >> 7)) * (3 * NH);
#pragma unroll
        for (int jj = 0; jj < 4; ++jj) {
          int jg = n0 + tn * 4 + jj;
          __hip_atomic_store(&gi_all[gb + jg], acc[i][jj] + b_ih[jg],
                             __ATOMIC_RELAXED, __HIP_MEMORY_SCOPE_AGENT);
        }
      }
      __syncthreads();   // drains stores (vmcnt) before the release-add
      if (tid == 0)
        __hip_atomic_fetch_add(&giflag[b * 2 + chunk], 1u, __ATOMIC_RELEASE, __HIP_MEMORY_SCOPE_AGENT);
    }
  }
  // ---- phase 1: out_w -> bf16 conv ----
  {
    long long n4 = (long long)NV * NH / 4;
    for (long long i = (long long)cid * 512 + tid; i < n4; i += (long long)128 * 512) {
      float4 v = ((const float4*)out_w)[i];
      union { __bf16 b[4]; float2 f2; } u;
      u.b[0] = (__bf16)v.x; u.b[1] = (__bf16)v.y; u.b[2] = (__bf16)v.z; u.b[3] = (__bf16)v.w;
      *((float2*)((__bf16*)owb + 4 * i)) = u.f2;
    }
  }
  // ---- phase 2: attention units ----
  float* hb = smem;            // [512]
  float* red = smem + 512;     // [512]
  float* wb = smem + 1024;     // [128]
  float* sred = smem + 1152;   // [2]
  for (int it = 0; it < 16; ++it) {
    const int u = it * 128 + cid;
    const int t = u >> 4, b = u & 15;
    if (tid == 0) {
      int guard = 0;
      while (__hip_atomic_load(&hdone[u], __ATOMIC_RELAXED, __HIP_MEMORY_SCOPE_AGENT) < 8u &&
             ++guard < (1 << 25)) {
        __builtin_amdgcn_s_sleep(4);
      }
    }
    __syncthreads();
    hb[tid] = __hip_atomic_load(&h_all[(long long)((t + 1) * 16 + b) * 512 + tid],
                                __ATOMIC_RELAXED, __HIP_MEMORY_SCOPE_AGENT);
    __syncthreads();
    {
      const int s = tid & 127, q = tid >> 7;
      const float* erow = enc + (long long)(b * 128 + s) * 512 + q * 128;
      float p = 0.f;
#pragma unroll 8
      for (int k = 0; k < 128; ++k) p = fmaf(hb[q * 128 + k], erow[k], p);
      red[tid] = p;
    }
    __syncthreads();
    float sc = 0.f;
    if (tid < 128) {
      sc = red[tid] + red[tid + 128] + red[tid + 256] + red[tid + 384];
      if (mask[b * 128 + tid] == 0) sc = -1e6f;
      wb[tid] = sc;
    }
    __syncthreads();
    if (tid < 64) {
      float m2 = fmaxf(wb[tid], wb[tid + 64]);
      for (int off = 32; off; off >>= 1) m2 = fmaxf(m2, __shfl_down(m2, off));
      if (tid == 0) sred[0] = m2;
    }
    __syncthreads();
    if (tid < 128) wb[tid] = expf(sc - sred[0]);
    __syncthreads();
    if (tid < 64) {
      float s2 = wb[tid] + wb[tid + 64];
      for (int off = 32; off; off >>= 1) s2 += __shfl_down(s2, off);
      if (tid == 0) sred[1] = s2;
    }
    __syncthreads();
    {
      float inv = 1.f / sred[1];
      if (tid < 128) {
        float w = wb[tid] * inv;
        wb[tid] = w;
        d_attn[(long long)u * 128 + tid] = w;
      }
    }
    __syncthreads();
    {
      float m = 0.f;
#pragma unroll 8
      for (int s2 = 0; s2 < 128; ++s2)
        m = fmaf(wb[s2], enc[(long long)(b * 128 + s2) * 512 + tid], m);
      mixb[(long long)(b * 128 + t) * 512 + tid] = m;
    }
    __syncthreads();
  }
}

// ---------------- K2: attended = tanh([h,mix] @ lin_out_w^T) -> bf16 ----------------
__global__ __launch_bounds__(256) void k_att_lin(const float* __restrict__ h_all,
                                                 const float* __restrict__ mix,
                                                 const float* __restrict__ W,
                                                 __bf16* __restrict__ attout) {
  __shared__ float As[16][64];
  __shared__ float Bs[16][64];
  const int tid = threadIdx.x;
  const int n0 = blockIdx.x * 64;
  const int m0 = blockIdx.y * 64;
  float acc[4][4] = {};
  const int rl = tid >> 2;
  const int kq = (tid & 3) * 4;
  const int tm = tid & 15, tn = tid >> 4;
  const int r_a = m0 + rl;
  const int b_a = r_a >> 7, t_a = r_a & 127;
  const float* hrow = h_all + (long long)((t_a + 1) * 16 + b_a) * 512;
  const float* mrow = mix + (long long)r_a * 512;
  for (int k0 = 0; k0 < 1024; k0 += 16) {
    __syncthreads();
    float4 av = (k0 < 512) ? *(const float4*)(hrow + k0 + kq)
                           : *(const float4*)(mrow + (k0 - 512) + kq);
    float4 bv = *(const float4*)(W + (long long)(n0 + rl) * 1024 + k0 + kq);
    As[kq + 0][rl] = av.x; As[kq + 1][rl] = av.y; As[kq + 2][rl] = av.z; As[kq + 3][rl] = av.w;
    Bs[kq + 0][rl] = bv.x; Bs[kq + 1][rl] = bv.y; Bs[kq + 2][rl] = bv.z; Bs[kq + 3][rl] = bv.w;
    __syncthreads();
#pragma unroll
    for (int kk = 0; kk < 16; ++kk) {
      float4 a = *(const float4*)&As[kk][tm * 4];
      float4 b = *(const float4*)&Bs[kk][tn * 4];
      float ar[4] = {a.x, a.y, a.z, a.w}, br[4] = {b.x, b.y, b.z, b.w};
#pragma unroll
      for (int i = 0; i < 4; ++i)
#pragma unroll
        for (int j = 0; j < 4; ++j) acc[i][j] = fmaf(ar[i], br[j], acc[i][j]);
    }
  }
#pragma unroll
  for (int i = 0; i < 4; ++i) {
    int r = m0 + tm * 4 + i;
#pragma unroll
    for (int j = 0; j < 4; ++j) {
      int o = n0 + tn * 4 + j;
      attout[(long long)r * 512 + o] = (__bf16)tanhf(acc[i][j]);
    }
  }
}

// ---------------- K3: scores = attended @ out_w^T + out_b  (bf16 MFMA, 128x128, f32 out) ----------------
__global__ __launch_bounds__(256) void k_out(const __bf16* __restrict__ Abf,
                                             const __bf16* __restrict__ Bbf,
                                             const float* __restrict__ bias,
                                             float* __restrict__ Cout) {
  __shared__ __bf16 Al[128 * 32];
  __shared__ __bf16 Bl[128 * 32];
  const int tid = threadIdx.x;
  const int lane = tid & 63;
  const int wave = tid >> 6;
  const int wm = wave >> 1, wn = wave & 1;
  const int swz = (blockIdx.x & 7) * 500 + (blockIdx.x >> 3);   // bijective (4000 % 8 == 0)
  const int m0 = (swz & 15) * 128, n0 = (swz >> 4) * 128;
  f32x4 acc[4][4] = {};
  const int lrow = lane >> 2;
  const int lcol = (lane & 3) * 8;
  const int lm = lane & 15, lc = lane >> 4;
  for (int ks = 0; ks < 16; ++ks) {
    const int k0 = ks * 32;
    __syncthreads();
#pragma unroll
    for (int i = 0; i < 2; ++i) {
      int chunk = wave * 2 + i;
      int r = chunk * 16 + lrow;
      const __bf16* ga = Abf + (long long)(m0 + r) * NH + k0 + lcol;
      const __bf16* gb = Bbf + (long long)(n0 + r) * NH + k0 + lcol;
      __builtin_amdgcn_global_load_lds((gu32*)ga, (lu32*)((char*)Al + chunk * 1024), 16, 0, 0);
      __builtin_amdgcn_global_load_lds((gu32*)gb, (lu32*)((char*)Bl + chunk * 1024), 16, 0, 0);
    }
    __syncthreads();
    bf16x8 af[4], bfr[4];
#pragma unroll
    for (int i = 0; i < 4; ++i) af[i] = *(const bf16x8*)&Al[(wm * 64 + i * 16 + lm) * 32 + lc * 8];
#pragma unroll
    for (int j = 0; j < 4; ++j) bfr[j] = *(const bf16x8*)&Bl[(wn * 64 + j * 16 + lm) * 32 + lc * 8];
#pragma unroll
    for (int i = 0; i < 4; ++i)
#pragma unroll
      for (int j = 0; j < 4; ++j)
        acc[i][j] = __builtin_amdgcn_mfma_f32_16x16x32_bf16(bfr[j], af[i], acc[i][j], 0, 0, 0);
  }
  float4 bv[4];
#pragma unroll
  for (int j = 0; j < 4; ++j)
    bv[j] = *(const float4*)&bias[n0 + wn * 64 + j * 16 + lc * 4];
#pragma unroll
  for (int i = 0; i < 4; ++i) {
    long long rbase = (long long)(m0 + wm * 64 + i * 16 + lm) * NV;
#pragma unroll
    for (int j = 0; j < 4; ++j) {
      int c = n0 + wn * 64 + j * 16 + lc * 4;
      float4 o;
      o.x = acc[i][j][0] + bv[j].x;
      o.y = acc[i][j][1] + bv[j].y;
      o.z = acc[i][j][2] + bv[j].z;
      o.w = acc[i][j][3] + bv[j].w;
      *(float4*)&Cout[rbase + c] = o;
    }
  }
}

// ---------------- launch ----------------
extern "C" void kernel_launch(void* const* d_in, const int* in_sizes, int n_in,
                              void* d_out, int out_size, void* d_ws, size_t ws_size,
                              hipStream_t stream) {
  const int* tv = (const int*)d_in[0];
  const float* dh = (const float*)d_in[1];
  const float* enc = (const float*)d_in[2];
  const int* mask = (const int*)d_in[3];
  const float* emb = (const float*)d_in[4];
  const float* w_ih = (const float*)d_in[5];
  const float* w_hh = (const float*)d_in[6];
  const float* b_ih = (const float*)d_in[7];
  const float* b_hh = (const float*)d_in[8];
  const float* lin_w = (const float*)d_in[9];
  const float* out_w = (const float*)d_in[10];
  const float* out_b = (const float*)d_in[11];
  float* dout = (float*)d_out;
  char* ws = (char*)d_ws;
  if (ws_size < WS_NEED) return;

  unsigned long long* htag = (unsigned long long*)(ws + HTAG_OFF);
  unsigned int* hdone = (unsigned int*)(ws + HDONE_OFF);
  unsigned int* giflag = (unsigned int*)(ws + GIF_OFF);
  float* gi_all = (float*)(ws + GI_OFF);
  float* h_all = (float*)(ws + HALL_OFF);
  float* mixb = (float*)(ws + MIX_OFF);
  __bf16* attb = (__bf16*)(ws + ATTB_OFF);
  __bf16* owb = (__bf16*)(ws + OWB_OFF);

  float* d_scores = dout;                                  // [B,T,V]
  float* d_hf = dout + (long long)NB * NT * NV;            // [1,B,H]
  float* d_attn = d_hf + NB * NH;                          // [T,B,S]

  // zero htag + hdone + giflag
  hipMemsetAsync(ws + HTAG_OFF, 0, GI_OFF - HTAG_OFF, stream);
  k_mid<<<256, 512, 0, stream>>>(w_hh, b_hh, dh, h_all, htag, hdone, giflag, gi_all,
                                 tv, emb, w_ih, b_ih, d_hf,
                                 enc, mask, out_w, owb, d_attn, mixb);
  k_att_lin<<<dim3(8, 32), 256, 0, stream>>>(h_all, mixb, lin_w, attb);
  k_out<<<4000, 256, 0, stream>>>(attb, owb, out_b, d_scores);
}

// Round 24
// 493.615 us; speedup vs baseline: 1.3946x; 1.3946x over previous
//
#include <hip/hip_runtime.h>
#include <hip/hip_bf16.h>

#define NV 32000
#define NE 512
#define NH 512
#define NB 16
#define NT 128
#define NS 128

typedef __bf16 bf16x8 __attribute__((ext_vector_type(8)));
typedef float f32x4 __attribute__((ext_vector_type(4)));
typedef const __attribute__((address_space(1))) unsigned int gu32;
typedef __attribute__((address_space(3))) unsigned int lu32;

// ---------------- workspace layout (bytes) ----------------
static constexpr size_t HTAG_OFF  = 0;                                    // [2][16][512] u64
static constexpr size_t HDONE_OFF = HTAG_OFF + (size_t)2*NB*NH*8;         // [2048] u32
static constexpr size_t GI_OFF    = HDONE_OFF + 8192;                     // [T][B][1536] f32
static constexpr size_t HALL_OFF  = GI_OFF + (size_t)NT*NB*3*NH*4;        // [T+1][B][512] f32
static constexpr size_t MIX_OFF   = HALL_OFF + (size_t)(NT+1)*NB*NH*4;    // [B*T][512] f32
static constexpr size_t ATTB_OFF  = MIX_OFF + (size_t)NB*NT*NH*4;         // [B*T][512] bf16
static constexpr size_t OWB_OFF   = ATTB_OFF + (size_t)NB*NT*NH*2;        // [V][512] bf16
static constexpr size_t WS_NEED   = OWB_OFF + (size_t)NV*NH*2;            // ~56 MB

// ---------------- K1: merged prep + gi ----------------
// blocks 0..767: gi GEMM; 768..799: h0/htag/hdone init
__global__ __launch_bounds__(256) void k_pg(const int* __restrict__ tv,
                                            const float* __restrict__ emb,
                                            const float* __restrict__ w_ih,
                                            const float* __restrict__ b_ih,
                                            float* __restrict__ gi_all,
                                            const float* __restrict__ dh,
                                            float* __restrict__ h_all,
                                            unsigned long long* __restrict__ htag,
                                            unsigned int* __restrict__ hdone) {
  __shared__ float sbuf[2048];
  const int g = blockIdx.x;
  const int tid = threadIdx.x;
  if (g >= 768) {
    long long i0 = (long long)(g - 768) * 256 + tid;
    long long stride = (long long)32 * 256;
    for (long long i = i0; i < NB * NH; i += stride) {
      float hv = dh[i];
      h_all[i] = hv;
      union { float f; unsigned u; } c; c.f = hv;
      htag[i] = (1ull << 32) | c.u;
      htag[NB * NH + i] = 0ull;
    }
    for (long long i = i0; i < 2048; i += stride) hdone[i] = 0u;
    return;
  }
  // ---- gi part ----
  float (*As)[64] = (float (*)[64])sbuf;
  float (*Bs)[64] = (float (*)[64])(sbuf + 1024);
  const int n0 = (g % 24) * 64;
  const int m0 = (g / 24) * 64;
  float acc[4][4] = {};
  const int rl = tid >> 2;
  const int kq = (tid & 3) * 4;
  const int tvr = tv[m0 + rl];
  const float* arow = emb + (long long)tvr * NE;
  const int tm = tid & 15, tn = tid >> 4;
  for (int k0 = 0; k0 < NE; k0 += 16) {
    __syncthreads();
    float4 av = make_float4(0.f, 0.f, 0.f, 0.f);
    if (tvr != 0) av = *(const float4*)(arow + k0 + kq);
    float4 bv = *(const float4*)(w_ih + (long long)(n0 + rl) * NE + k0 + kq);
    As[kq + 0][rl] = av.x; As[kq + 1][rl] = av.y; As[kq + 2][rl] = av.z; As[kq + 3][rl] = av.w;
    Bs[kq + 0][rl] = bv.x; Bs[kq + 1][rl] = bv.y; Bs[kq + 2][rl] = bv.z; Bs[kq + 3][rl] = bv.w;
    __syncthreads();
#pragma unroll
    for (int kk = 0; kk < 16; ++kk) {
      float4 a = *(const float4*)&As[kk][tm * 4];
      float4 b = *(const float4*)&Bs[kk][tn * 4];
      float ar[4] = {a.x, a.y, a.z, a.w}, br[4] = {b.x, b.y, b.z, b.w};
#pragma unroll
      for (int i = 0; i < 4; ++i)
#pragma unroll
        for (int j = 0; j < 4; ++j) acc[i][j] = fmaf(ar[i], br[j], acc[i][j]);
    }
  }
#pragma unroll
  for (int i = 0; i < 4; ++i) {
    int r = m0 + tm * 4 + i;
    long long gb = (long long)((r & 127) * 16 + (r >> 7)) * (3 * NH);
#pragma unroll
    for (int j = 0; j < 4; ++j) {
      int jg = n0 + tn * 4 + j;
      gi_all[gb + jg] = acc[i][j] + b_ih[jg];
    }
  }
}

// ---------------- K2: k_mid — rec (0..127) || conv+attn (128..255) ----------------
// 256 blocks x 512 threads; 84KB LDS -> 1 block/CU (CU-exclusive), no VGPR spill.
__global__ __launch_bounds__(512, 1) void k_mid(const float* __restrict__ w_hh,
                                                const float* __restrict__ gi_all,
                                                const float* __restrict__ b_hh,
                                                const float* __restrict__ dh,
                                                float* __restrict__ h_all,
                                                unsigned long long* __restrict__ htag,
                                                unsigned int* __restrict__ hdone,
                                                float* __restrict__ d_hf,
                                                const float* __restrict__ enc,
                                                const int* __restrict__ mask,
                                                const float* __restrict__ out_w,
                                                __bf16* __restrict__ owb,
                                                float* __restrict__ d_attn,
                                                float* __restrict__ mixb) {
  __shared__ char smem_raw[86016];   // 84 KB fences to 1 block/CU
  float* smem = (float*)smem_raw;
  const int tid = threadIdx.x;
  const int bid = blockIdx.x;

  if (bid < 128) {
    const int b = bid & 15, sub = bid >> 4;
    const int hl = tid & 63, kc = tid >> 6;
    const int j = sub * 64 + hl;
    float* hbuf = smem;
    float* part = smem + 512;

    float wg[3][64];
#pragma unroll
    for (int g = 0; g < 3; ++g) {
      const float* wp = w_hh + (long long)(g * 512 + j) * NH + kc * 64;
#pragma unroll
      for (int q4 = 0; q4 < 16; ++q4) {
        float4 w4 = *(const float4*)(wp + q4 * 4);
        wg[g][q4 * 4 + 0] = w4.x; wg[g][q4 * 4 + 1] = w4.y;
        wg[g][q4 * 4 + 2] = w4.z; wg[g][q4 * 4 + 3] = w4.w;
      }
    }
    float bhr = 0.f, bhz = 0.f, bhn = 0.f;
    if (tid < 64) {
      bhr = b_hh[sub * 64 + tid];
      bhz = b_hh[512 + sub * 64 + tid];
      bhn = b_hh[1024 + sub * 64 + tid];
    }

    for (int t = 0; t < NT; ++t) {
      float gr = 0.f, gz = 0.f, gn = 0.f;
      if (tid < 64) {
        const float* gi = gi_all + (long long)(t * 16 + b) * 1536;
        gr = gi[sub * 64 + tid];
        gz = gi[512 + sub * 64 + tid];
        gn = gi[1024 + sub * 64 + tid];
      }
      if (t == 0) {
        hbuf[tid] = dh[b * 512 + tid];
      } else {
        unsigned long long* slot = htag + ((long long)(t & 1) * NB + b) * 512 + tid;
        unsigned long long v = __hip_atomic_load(slot, __ATOMIC_RELAXED, __HIP_MEMORY_SCOPE_AGENT);
        int guard = 0;
        while ((unsigned)(v >> 32) != (unsigned)(t + 1) && ++guard < (1 << 22)) {
          v = __hip_atomic_load(slot, __ATOMIC_RELAXED, __HIP_MEMORY_SCOPE_AGENT);
        }
        union { unsigned u; float f; } c; c.u = (unsigned)v;
        hbuf[tid] = c.f;
      }
      __syncthreads();
      float ar = 0.f, az = 0.f, an = 0.f;
#pragma unroll
      for (int q4 = 0; q4 < 4; ++q4) {
        float4 h4[4];
#pragma unroll
        for (int u = 0; u < 4; ++u) h4[u] = *(const float4*)&hbuf[kc * 64 + q4 * 16 + u * 4];
#pragma unroll
        for (int u = 0; u < 4; ++u) {
          const float hh[4] = {h4[u].x, h4[u].y, h4[u].z, h4[u].w};
#pragma unroll
          for (int v = 0; v < 4; ++v) {
            const int q = q4 * 16 + u * 4 + v;
            ar = fmaf(hh[v], wg[0][q], ar);
            az = fmaf(hh[v], wg[1][q], az);
            an = fmaf(hh[v], wg[2][q], an);
          }
        }
      }
      part[(0 * 8 + kc) * 64 + hl] = ar;
      part[(1 * 8 + kc) * 64 + hl] = az;
      part[(2 * 8 + kc) * 64 + hl] = an;
      __syncthreads();
      if (tid < 64) {
        float sr = bhr, sz = bhz, sn = bhn;
#pragma unroll
        for (int c = 0; c < 8; ++c) {
          sr += part[(0 * 8 + c) * 64 + tid];
          sz += part[(1 * 8 + c) * 64 + tid];
          sn += part[(2 * 8 + c) * 64 + tid];
        }
        float r = 1.f / (1.f + expf(-(gr + sr)));
        float z = 1.f / (1.f + expf(-(gz + sz)));
        float n = tanhf(gn + r * sn);
        float hp = hbuf[sub * 64 + tid];
        float hv = (1.f - z) * n + z * hp;
        if (t < NT - 1) {
          union { float f; unsigned u; } c2; c2.f = hv;
          unsigned long long out = ((unsigned long long)(unsigned)(t + 2) << 32) | c2.u;
          __hip_atomic_store(htag + ((long long)((t + 1) & 1) * NB + b) * 512 + sub * 64 + tid, out,
                             __ATOMIC_RELAXED, __HIP_MEMORY_SCOPE_AGENT);
        }
        __hip_atomic_store(&h_all[(long long)((t + 1) * 16 + b) * 512 + sub * 64 + tid], hv,
                           __ATOMIC_RELAXED, __HIP_MEMORY_SCOPE_AGENT);
        if (t == NT - 1) d_hf[b * 512 + sub * 64 + tid] = hv;
      }
      __syncthreads();
      if (tid == 0)
        __hip_atomic_fetch_add(&hdone[t * 16 + b], 1u, __ATOMIC_RELAXED, __HIP_MEMORY_SCOPE_AGENT);
    }
    return;
  }

  // ================= conv + attention consumers (512 threads) =================
  const int cid = bid - 128;
  {
    long long n4 = (long long)NV * NH / 4;
    for (long long i = (long long)cid * 512 + tid; i < n4; i += (long long)128 * 512) {
      float4 v = ((const float4*)out_w)[i];
      union { __bf16 b[4]; float2 f2; } u;
      u.b[0] = (__bf16)v.x; u.b[1] = (__bf16)v.y; u.b[2] = (__bf16)v.z; u.b[3] = (__bf16)v.w;
      *((float2*)((__bf16*)owb + 4 * i)) = u.f2;
    }
  }
  float* hb = smem;            // [512]
  float* red = smem + 512;     // [512]
  float* wb = smem + 1024;     // [128]
  float* sred = smem + 1152;   // [2]
  for (int it = 0; it < 16; ++it) {
    const int u = it * 128 + cid;
    const int t = u >> 4, b = u & 15;
    if (tid == 0) {
      int guard = 0;
      while (__hip_atomic_load(&hdone[u], __ATOMIC_RELAXED, __HIP_MEMORY_SCOPE_AGENT) < 8u &&
             ++guard < (1 << 25)) {
        __builtin_amdgcn_s_sleep(4);
      }
    }
    __syncthreads();
    hb[tid] = __hip_atomic_load(&h_all[(long long)((t + 1) * 16 + b) * 512 + tid],
                                __ATOMIC_RELAXED, __HIP_MEMORY_SCOPE_AGENT);
    __syncthreads();
    {
      const int s = tid & 127, q = tid >> 7;
      const float* erow = enc + (long long)(b * 128 + s) * 512 + q * 128;
      float p = 0.f;
#pragma unroll 8
      for (int k = 0; k < 128; ++k) p = fmaf(hb[q * 128 + k], erow[k], p);
      red[tid] = p;
    }
    __syncthreads();
    float sc = 0.f;
    if (tid < 128) {
      sc = red[tid] + red[tid + 128] + red[tid + 256] + red[tid + 384];
      if (mask[b * 128 + tid] == 0) sc = -1e6f;
      wb[tid] = sc;
    }
    __syncthreads();
    if (tid < 64) {
      float m2 = fmaxf(wb[tid], wb[tid + 64]);
      for (int off = 32; off; off >>= 1) m2 = fmaxf(m2, __shfl_down(m2, off));
      if (tid == 0) sred[0] = m2;
    }
    __syncthreads();
    if (tid < 128) wb[tid] = expf(sc - sred[0]);
    __syncthreads();
    if (tid < 64) {
      float s2 = wb[tid] + wb[tid + 64];
      for (int off = 32; off; off >>= 1) s2 += __shfl_down(s2, off);
      if (tid == 0) sred[1] = s2;
    }
    __syncthreads();
    {
      float inv = 1.f / sred[1];
      if (tid < 128) {
        float w = wb[tid] * inv;
        wb[tid] = w;
        d_attn[(long long)u * 128 + tid] = w;
      }
    }
    __syncthreads();
    {
      float m = 0.f;
#pragma unroll 8
      for (int s2 = 0; s2 < 128; ++s2)
        m = fmaf(wb[s2], enc[(long long)(b * 128 + s2) * 512 + tid], m);
      mixb[(long long)(b * 128 + t) * 512 + tid] = m;
    }
    __syncthreads();
  }
}

// ---------------- K3: attended = tanh([h,mix] @ lin_out_w^T) -> bf16 ----------------
__global__ __launch_bounds__(256) void k_att_lin(const float* __restrict__ h_all,
                                                 const float* __restrict__ mix,
                                                 const float* __restrict__ W,
                                                 __bf16* __restrict__ attout) {
  __shared__ float As[16][64];
  __shared__ float Bs[16][64];
  const int tid = threadIdx.x;
  const int n0 = blockIdx.x * 64;
  const int m0 = blockIdx.y * 64;
  float acc[4][4] = {};
  const int rl = tid >> 2;
  const int kq = (tid & 3) * 4;
  const int tm = tid & 15, tn = tid >> 4;
  const int r_a = m0 + rl;
  const int b_a = r_a >> 7, t_a = r_a & 127;
  const float* hrow = h_all + (long long)((t_a + 1) * 16 + b_a) * 512;
  const float* mrow = mix + (long long)r_a * 512;
  for (int k0 = 0; k0 < 1024; k0 += 16) {
    __syncthreads();
    float4 av = (k0 < 512) ? *(const float4*)(hrow + k0 + kq)
                           : *(const float4*)(mrow + (k0 - 512) + kq);
    float4 bv = *(const float4*)(W + (long long)(n0 + rl) * 1024 + k0 + kq);
    As[kq + 0][rl] = av.x; As[kq + 1][rl] = av.y; As[kq + 2][rl] = av.z; As[kq + 3][rl] = av.w;
    Bs[kq + 0][rl] = bv.x; Bs[kq + 1][rl] = bv.y; Bs[kq + 2][rl] = bv.z; Bs[kq + 3][rl] = bv.w;
    __syncthreads();
#pragma unroll
    for (int kk = 0; kk < 16; ++kk) {
      float4 a = *(const float4*)&As[kk][tm * 4];
      float4 b = *(const float4*)&Bs[kk][tn * 4];
      float ar[4] = {a.x, a.y, a.z, a.w}, br[4] = {b.x, b.y, b.z, b.w};
#pragma unroll
      for (int i = 0; i < 4; ++i)
#pragma unroll
        for (int j = 0; j < 4; ++j) acc[i][j] = fmaf(ar[i], br[j], acc[i][j]);
    }
  }
#pragma unroll
  for (int i = 0; i < 4; ++i) {
    int r = m0 + tm * 4 + i;
#pragma unroll
    for (int j = 0; j < 4; ++j) {
      int o = n0 + tn * 4 + j;
      attout[(long long)r * 512 + o] = (__bf16)tanhf(acc[i][j]);
    }
  }
}

// ---------------- K4: scores = attended @ out_w^T + out_b  (bf16 MFMA, 128x128, f32 out) ----------------
__global__ __launch_bounds__(256) void k_out(const __bf16* __restrict__ Abf,
                                             const __bf16* __restrict__ Bbf,
                                             const float* __restrict__ bias,
                                             float* __restrict__ Cout) {
  __shared__ __bf16 Al[128 * 32];
  __shared__ __bf16 Bl[128 * 32];
  const int tid = threadIdx.x;
  const int lane = tid & 63;
  const int wave = tid >> 6;
  const int wm = wave >> 1, wn = wave & 1;
  const int swz = (blockIdx.x & 7) * 500 + (blockIdx.x >> 3);   // bijective (4000 % 8 == 0)
  const int m0 = (swz & 15) * 128, n0 = (swz >> 4) * 128;
  f32x4 acc[4][4] = {};
  const int lrow = lane >> 2;
  const int lcol = (lane & 3) * 8;
  const int lm = lane & 15, lc = lane >> 4;
  for (int ks = 0; ks < 16; ++ks) {
    const int k0 = ks * 32;
    __syncthreads();
#pragma unroll
    for (int i = 0; i < 2; ++i) {
      int chunk = wave * 2 + i;
      int r = chunk * 16 + lrow;
      const __bf16* ga = Abf + (long long)(m0 + r) * NH + k0 + lcol;
      const __bf16* gb = Bbf + (long long)(n0 + r) * NH + k0 + lcol;
      __builtin_amdgcn_global_load_lds((gu32*)ga, (lu32*)((char*)Al + chunk * 1024), 16, 0, 0);
      __builtin_amdgcn_global_load_lds((gu32*)gb, (lu32*)((char*)Bl + chunk * 1024), 16, 0, 0);
    }
    __syncthreads();
    bf16x8 af[4], bfr[4];
#pragma unroll
    for (int i = 0; i < 4; ++i) af[i] = *(const bf16x8*)&Al[(wm * 64 + i * 16 + lm) * 32 + lc * 8];
#pragma unroll
    for (int j = 0; j < 4; ++j) bfr[j] = *(const bf16x8*)&Bl[(wn * 64 + j * 16 + lm) * 32 + lc * 8];
#pragma unroll
    for (int i = 0; i < 4; ++i)
#pragma unroll
      for (int j = 0; j < 4; ++j)
        acc[i][j] = __builtin_amdgcn_mfma_f32_16x16x32_bf16(bfr[j], af[i], acc[i][j], 0, 0, 0);
  }
  float4 bv[4];
#pragma unroll
  for (int j = 0; j < 4; ++j)
    bv[j] = *(const float4*)&bias[n0 + wn * 64 + j * 16 + lc * 4];
#pragma unroll
  for (int i = 0; i < 4; ++i) {
    long long rbase = (long long)(m0 + wm * 64 + i * 16 + lm) * NV;
#pragma unroll
    for (int j = 0; j < 4; ++j) {
      int c = n0 + wn * 64 + j * 16 + lc * 4;
      float4 o;
      o.x = acc[i][j][0] + bv[j].x;
      o.y = acc[i][j][1] + bv[j].y;
      o.z = acc[i][j][2] + bv[j].z;
      o.w = acc[i][j][3] + bv[j].w;
      *(float4*)&Cout[rbase + c] = o;
    }
  }
}

// ---------------- launch ----------------
extern "C" void kernel_launch(void* const* d_in, const int* in_sizes, int n_in,
                              void* d_out, int out_size, void* d_ws, size_t ws_size,
                              hipStream_t stream) {
  const int* tv = (const int*)d_in[0];
  const float* dh = (const float*)d_in[1];
  const float* enc = (const float*)d_in[2];
  const int* mask = (const int*)d_in[3];
  const float* emb = (const float*)d_in[4];
  const float* w_ih = (const float*)d_in[5];
  const float* w_hh = (const float*)d_in[6];
  const float* b_ih = (const float*)d_in[7];
  const float* b_hh = (const float*)d_in[8];
  const float* lin_w = (const float*)d_in[9];
  const float* out_w = (const float*)d_in[10];
  const float* out_b = (const float*)d_in[11];
  float* dout = (float*)d_out;
  char* ws = (char*)d_ws;
  if (ws_size < WS_NEED) return;

  unsigned long long* htag = (unsigned long long*)(ws + HTAG_OFF);
  unsigned int* hdone = (unsigned int*)(ws + HDONE_OFF);
  float* gi_all = (float*)(ws + GI_OFF);
  float* h_all = (float*)(ws + HALL_OFF);
  float* mixb = (float*)(ws + MIX_OFF);
  __bf16* attb = (__bf16*)(ws + ATTB_OFF);
  __bf16* owb = (__bf16*)(ws + OWB_OFF);

  float* d_scores = dout;                                  // [B,T,V]
  float* d_hf = dout + (long long)NB * NT * NV;            // [1,B,H]
  float* d_attn = d_hf + NB * NH;                          // [T,B,S]

  k_pg<<<800, 256, 0, stream>>>(tv, emb, w_ih, b_ih, gi_all, dh, h_all, htag, hdone);
  k_mid<<<256, 512, 0, stream>>>(w_hh, gi_all, b_hh, dh, h_all, htag, hdone, d_hf,
                                 enc, mask, out_w, owb, d_attn, mixb);
  k_att_lin<<<dim3(8, 32), 256, 0, stream>>>(h_all, mixb, lin_w, attb);
  k_out<<<4000, 256, 0, stream>>>(attb, owb, out_b, d_scores);
}